// Round 1
// baseline (2279.700 us; speedup 1.0000x reference)
//
#include <hip/hip_runtime.h>
#include <hip/hip_bf16.h>
#include <math.h>

// Problem constants
constexpr int N_ROWS = 32768;
constexpr int K_DIM  = 4096;
constexpr int R_DIM  = 256;

// ---------------------------------------------------------------------------
// 128x128-tile fp32 GEMM, BK=16, 256 threads, 8x8 micro-tile per thread.
//   C[m,n] = sum_k A[m,k] * (BT ? B[n,k] : B[k,n])
// A is M x Kc row-major. B is (BT ? N x Kc : Kc x N) row-major.
// All dims assumed divisible by tile sizes (true for this problem).
// ---------------------------------------------------------------------------
template<bool BT>
__global__ __launch_bounds__(256)
void gemm128(const float* __restrict__ A, const float* __restrict__ B,
             float* __restrict__ C, int M, int N, int Kc)
{
    __shared__ __align__(16) float As[16][132];   // [k][m], +4 pad keeps f4 align
    __shared__ __align__(16) float Bs[16][132];   // [k][n]

    const int tid = threadIdx.x;
    const int tx = tid & 15;   // col group 0..15
    const int ty = tid >> 4;   // row group 0..15
    const long m0 = (long)blockIdx.x * 128;
    const long n0 = (long)blockIdx.y * 128;

    float acc[8][8];
#pragma unroll
    for (int i = 0; i < 8; ++i)
#pragma unroll
        for (int j = 0; j < 8; ++j) acc[i][j] = 0.f;

    for (int k0 = 0; k0 < Kc; k0 += 16) {
        // ---- stage A tile: 128 rows x 16 cols, transposed into As[k][m]
#pragma unroll
        for (int q = 0; q < 2; ++q) {
            int fi  = tid + 256 * q;        // float4 index 0..511
            int row = fi >> 2;              // 0..127
            int col = (fi & 3) * 4;         // 0,4,8,12
            float4 v = *reinterpret_cast<const float4*>(
                A + (m0 + row) * (long)Kc + k0 + col);
            As[col + 0][row] = v.x;
            As[col + 1][row] = v.y;
            As[col + 2][row] = v.z;
            As[col + 3][row] = v.w;
        }
        // ---- stage B tile
        if (BT) {
            // B: N x Kc row-major; tile rows n0..n0+127, cols k0..k0+15
#pragma unroll
            for (int q = 0; q < 2; ++q) {
                int fi  = tid + 256 * q;
                int row = fi >> 2;
                int col = (fi & 3) * 4;
                float4 v = *reinterpret_cast<const float4*>(
                    B + (n0 + row) * (long)Kc + k0 + col);
                Bs[col + 0][row] = v.x;
                Bs[col + 1][row] = v.y;
                Bs[col + 2][row] = v.z;
                Bs[col + 3][row] = v.w;
            }
        } else {
            // B: Kc x N row-major; tile rows k0..k0+15, cols n0..n0+127
#pragma unroll
            for (int q = 0; q < 2; ++q) {
                int fi  = tid + 256 * q;
                int row = fi >> 5;          // 0..15
                int col = (fi & 31) * 4;    // 0..124
                float4 v = *reinterpret_cast<const float4*>(
                    B + (k0 + row) * (long)N + n0 + col);
                *reinterpret_cast<float4*>(&Bs[row][col]) = v;
            }
        }
        __syncthreads();

        // ---- 16 k-steps, 64 FMA each (8x8)
#pragma unroll
        for (int kk = 0; kk < 16; ++kk) {
            float a[8], b[8];
            *reinterpret_cast<float4*>(&a[0]) =
                *reinterpret_cast<const float4*>(&As[kk][ty * 8]);
            *reinterpret_cast<float4*>(&a[4]) =
                *reinterpret_cast<const float4*>(&As[kk][ty * 8 + 4]);
            *reinterpret_cast<float4*>(&b[0]) =
                *reinterpret_cast<const float4*>(&Bs[kk][tx * 8]);
            *reinterpret_cast<float4*>(&b[4]) =
                *reinterpret_cast<const float4*>(&Bs[kk][tx * 8 + 4]);
#pragma unroll
            for (int i = 0; i < 8; ++i)
#pragma unroll
                for (int j = 0; j < 8; ++j)
                    acc[i][j] = fmaf(a[i], b[j], acc[i][j]);
        }
        __syncthreads();
    }

    // ---- write 8x8 micro-tile (two float4 per row)
#pragma unroll
    for (int i = 0; i < 8; ++i) {
        float* p = C + (m0 + ty * 8 + i) * (long)N + n0 + tx * 8;
        float4 v0 = make_float4(acc[i][0], acc[i][1], acc[i][2], acc[i][3]);
        float4 v1 = make_float4(acc[i][4], acc[i][5], acc[i][6], acc[i][7]);
        *reinterpret_cast<float4*>(p)     = v0;
        *reinterpret_cast<float4*>(p + 4) = v1;
    }
}

// ---------------------------------------------------------------------------
// In-place row softmax over K_DIM=4096 columns. One 256-thread block per row;
// each thread owns 16 elements (4 float4). Block reduce max, then sum.
// ---------------------------------------------------------------------------
__global__ __launch_bounds__(256)
void softmax_rows(float* __restrict__ Mio)
{
    const long n  = blockIdx.x;
    float* row    = Mio + n * (long)K_DIM;
    const int tid = threadIdx.x;

    float4 v[4];
    float lmax = -3.4e38f;
#pragma unroll
    for (int q = 0; q < 4; ++q) {
        v[q] = reinterpret_cast<const float4*>(row)[tid + 256 * q];
        lmax = fmaxf(lmax,
                     fmaxf(fmaxf(v[q].x, v[q].y), fmaxf(v[q].z, v[q].w)));
    }

    __shared__ float redmax[4];
    __shared__ float redsum[4];
#pragma unroll
    for (int off = 32; off > 0; off >>= 1)
        lmax = fmaxf(lmax, __shfl_xor(lmax, off));
    if ((tid & 63) == 0) redmax[tid >> 6] = lmax;
    __syncthreads();
    const float gmax = fmaxf(fmaxf(redmax[0], redmax[1]),
                             fmaxf(redmax[2], redmax[3]));

    float lsum = 0.f;
#pragma unroll
    for (int q = 0; q < 4; ++q) {
        v[q].x = __expf(v[q].x - gmax);
        v[q].y = __expf(v[q].y - gmax);
        v[q].z = __expf(v[q].z - gmax);
        v[q].w = __expf(v[q].w - gmax);
        lsum += v[q].x + v[q].y + v[q].z + v[q].w;
    }
#pragma unroll
    for (int off = 32; off > 0; off >>= 1)
        lsum += __shfl_xor(lsum, off);
    if ((tid & 63) == 0) redsum[tid >> 6] = lsum;
    __syncthreads();
    const float inv = 1.f / (redsum[0] + redsum[1] + redsum[2] + redsum[3]);

#pragma unroll
    for (int q = 0; q < 4; ++q) {
        v[q].x *= inv; v[q].y *= inv; v[q].z *= inv; v[q].w *= inv;
        reinterpret_cast<float4*>(row)[tid + 256 * q] = v[q];
    }
}

// ---------------------------------------------------------------------------
// Launch: P = H@W_I (into C slot) ; M = P@L^T (into A slot) ; softmax rows ;
// C = A@L (overwrites P in C slot).  No workspace needed.
// ---------------------------------------------------------------------------
extern "C" void kernel_launch(void* const* d_in, const int* in_sizes, int n_in,
                              void* d_out, int out_size, void* d_ws, size_t ws_size,
                              hipStream_t stream)
{
    const float* H  = (const float*)d_in[0];   // N_ROWS x R_DIM
    const float* L  = (const float*)d_in[1];   // K_DIM  x R_DIM
    const float* Wi = (const float*)d_in[2];   // R_DIM  x R_DIM

    float* Cout = (float*)d_out;                                   // N x R
    float* Aout = (float*)d_out + (size_t)N_ROWS * R_DIM;          // N x K

    // K1: P = H @ W_I  (NN), stored temporarily in the C_I output slot
    gemm128<false><<<dim3(N_ROWS / 128, R_DIM / 128), 256, 0, stream>>>(
        H, Wi, Cout, N_ROWS, R_DIM, R_DIM);

    // K2: M = P @ L^T  (NT), logits into the A_I output slot
    gemm128<true><<<dim3(N_ROWS / 128, K_DIM / 128), 256, 0, stream>>>(
        Cout, L, Aout, N_ROWS, K_DIM, R_DIM);

    // K3: row softmax in place
    softmax_rows<<<dim3(N_ROWS), 256, 0, stream>>>(Aout);

    // K4: C = A @ L  (NN), overwrites P with the final C_I
    gemm128<false><<<dim3(N_ROWS / 128, R_DIM / 128), 256, 0, stream>>>(
        Aout, L, Cout, N_ROWS, R_DIM, K_DIM);
}

// Round 2
// 1281.399 us; speedup vs baseline: 1.7791x; 1.7791x over previous
//
#include <hip/hip_runtime.h>
#include <hip/hip_bf16.h>
#include <math.h>
#include <stdint.h>

// Problem constants
constexpr int N_ROWS = 32768;
constexpr int K_DIM  = 4096;
constexpr int R_DIM  = 256;
constexpr int KP     = 3 * R_DIM;   // 768: split-K' for [hi|hi|lo] x [hi|lo|hi]

typedef __bf16 bf16x8 __attribute__((ext_vector_type(8)));
typedef float  f32x4  __attribute__((ext_vector_type(4)));
typedef unsigned short u16x8 __attribute__((ext_vector_type(8)));

// ---- bf16 helpers (round-to-nearest-even; inputs are finite normals) ----
__device__ __forceinline__ unsigned short f2bf(float x) {
    unsigned u = __float_as_uint(x);
    u += 0x7fffu + ((u >> 16) & 1u);
    return (unsigned short)(u >> 16);
}
__device__ __forceinline__ float bf2f(unsigned short h) {
    return __uint_as_float((unsigned)h << 16);
}

// ---- async global->LDS, 16B per lane, LDS dest = wave-uniform base + lane*16
__device__ __forceinline__ void gl2lds16(const void* gptr, void* lptr) {
    __builtin_amdgcn_global_load_lds(
        (const __attribute__((address_space(1))) unsigned int*)gptr,
        (__attribute__((address_space(3))) unsigned int*)lptr,
        16, 0, 0);
}

// ===========================================================================
// MFMA NT GEMM: C[m,n] = sum_k A[m,k]*B[n,k], A/B bf16 k-major, C fp32.
// 128x128 tile, BK=32, 256 threads = 4 waves (2x2 of 64x64), 16x16x32 MFMA.
// M%128==0, N%128==0, Kc%32==0. m97-style: global_load_lds + 2 barriers.
// ===========================================================================
__global__ __launch_bounds__(256)
void gemm_mfma_nt(const unsigned short* __restrict__ A,
                  const unsigned short* __restrict__ B,
                  float* __restrict__ C, int M, int N, int Kc)
{
    __shared__ __align__(16) unsigned short As[128 * 32];
    __shared__ __align__(16) unsigned short Bs[128 * 32];

    const int tid  = threadIdx.x;
    const int wave = tid >> 6, lane = tid & 63;
    const int wm = wave >> 1, wn = wave & 1;
    const long m0 = (long)blockIdx.x * 128;
    const long n0 = (long)blockIdx.y * 128;

    f32x4 acc[4][4] = {};

    const int srow  = lane >> 2;        // 0..15 within 16-row chunk
    const int skoff = (lane & 3) * 8;   // bf16 elem offset within 32-wide row
    const int c0 = wave, c1 = wave + 4; // each wave stages 2 chunks per tile
    const int kq = (lane >> 4) * 8;     // frag k-offset 0,8,16,24
    const int mr = lane & 15;

    for (int k0 = 0; k0 < Kc; k0 += 32) {
        gl2lds16(A + (m0 + c0 * 16 + srow) * (long)Kc + k0 + skoff, &As[c0 * 512]);
        gl2lds16(A + (m0 + c1 * 16 + srow) * (long)Kc + k0 + skoff, &As[c1 * 512]);
        gl2lds16(B + (n0 + c0 * 16 + srow) * (long)Kc + k0 + skoff, &Bs[c0 * 512]);
        gl2lds16(B + (n0 + c1 * 16 + srow) * (long)Kc + k0 + skoff, &Bs[c1 * 512]);
        __syncthreads();

        bf16x8 af[4], bfr[4];
#pragma unroll
        for (int t = 0; t < 4; ++t) {
            af[t]  = *(const bf16x8*)&As[(wm * 64 + t * 16 + mr) * 32 + kq];
            bfr[t] = *(const bf16x8*)&Bs[(wn * 64 + t * 16 + mr) * 32 + kq];
        }
#pragma unroll
        for (int i = 0; i < 4; ++i)
#pragma unroll
            for (int j = 0; j < 4; ++j)
                acc[i][j] = __builtin_amdgcn_mfma_f32_16x16x32_bf16(
                    af[i], bfr[j], acc[i][j], 0, 0, 0);
        __syncthreads();
    }

    // C/D layout: col = lane&15, row = (lane>>4)*4 + reg
    const int col = lane & 15, rquad = (lane >> 4) * 4;
#pragma unroll
    for (int i = 0; i < 4; ++i) {
        const long mrow = m0 + wm * 64 + i * 16 + rquad;
#pragma unroll
        for (int j = 0; j < 4; ++j) {
            float* p = C + mrow * (long)N + n0 + wn * 64 + j * 16 + col;
#pragma unroll
            for (int r = 0; r < 4; ++r) p[(long)r * N] = acc[i][j][r];
        }
    }
}

// ===========================================================================
// MFMA NT GEMM with fp32 A converted to bf16 during staging (for C = A_sm@L).
// A: M x Kc fp32 k-major. B: N x Kc bf16 k-major (pre-transposed L). C fp32.
// ===========================================================================
__global__ __launch_bounds__(256)
void gemm_mfma_a32(const float* __restrict__ A,
                   const unsigned short* __restrict__ B,
                   float* __restrict__ C, int M, int N, int Kc)
{
    __shared__ __align__(16) unsigned short As[128 * 32];
    __shared__ __align__(16) unsigned short Bs[128 * 32];

    const int tid  = threadIdx.x;
    const int wave = tid >> 6, lane = tid & 63;
    const int wm = wave >> 1, wn = wave & 1;
    const long m0 = (long)blockIdx.x * 128;
    const long n0 = (long)blockIdx.y * 128;

    f32x4 acc[4][4] = {};

    const int srow  = lane >> 2;
    const int skoff = (lane & 3) * 8;
    const int c0 = wave, c1 = wave + 4;
    const int kq = (lane >> 4) * 8;
    const int mr = lane & 15;

    // A staging: thread t owns row = t>>1, k-half = (t&1)*16 (16 floats)
    const int arow  = tid >> 1;
    const int ahalf = (tid & 1) * 16;

    for (int k0 = 0; k0 < Kc; k0 += 32) {
        // B via async DMA
        gl2lds16(B + (n0 + c0 * 16 + srow) * (long)Kc + k0 + skoff, &Bs[c0 * 512]);
        gl2lds16(B + (n0 + c1 * 16 + srow) * (long)Kc + k0 + skoff, &Bs[c1 * 512]);
        // A: load fp32, convert, store bf16
        {
            const float* g = A + (m0 + arow) * (long)Kc + k0 + ahalf;
            float4 v0 = *(const float4*)(g + 0);
            float4 v1 = *(const float4*)(g + 4);
            float4 v2 = *(const float4*)(g + 8);
            float4 v3 = *(const float4*)(g + 12);
            u16x8 u0, u1;
            u0[0] = f2bf(v0.x); u0[1] = f2bf(v0.y); u0[2] = f2bf(v0.z); u0[3] = f2bf(v0.w);
            u0[4] = f2bf(v1.x); u0[5] = f2bf(v1.y); u0[6] = f2bf(v1.z); u0[7] = f2bf(v1.w);
            u1[0] = f2bf(v2.x); u1[1] = f2bf(v2.y); u1[2] = f2bf(v2.z); u1[3] = f2bf(v2.w);
            u1[4] = f2bf(v3.x); u1[5] = f2bf(v3.y); u1[6] = f2bf(v3.z); u1[7] = f2bf(v3.w);
            *(u16x8*)&As[arow * 32 + ahalf + 0] = u0;
            *(u16x8*)&As[arow * 32 + ahalf + 8] = u1;
        }
        __syncthreads();

        bf16x8 af[4], bfr[4];
#pragma unroll
        for (int t = 0; t < 4; ++t) {
            af[t]  = *(const bf16x8*)&As[(wm * 64 + t * 16 + mr) * 32 + kq];
            bfr[t] = *(const bf16x8*)&Bs[(wn * 64 + t * 16 + mr) * 32 + kq];
        }
#pragma unroll
        for (int i = 0; i < 4; ++i)
#pragma unroll
            for (int j = 0; j < 4; ++j)
                acc[i][j] = __builtin_amdgcn_mfma_f32_16x16x32_bf16(
                    af[i], bfr[j], acc[i][j], 0, 0, 0);
        __syncthreads();
    }

    const int col = lane & 15, rquad = (lane >> 4) * 4;
#pragma unroll
    for (int i = 0; i < 4; ++i) {
        const long mrow = m0 + wm * 64 + i * 16 + rquad;
#pragma unroll
        for (int j = 0; j < 4; ++j) {
            float* p = C + mrow * (long)N + n0 + wn * 64 + j * 16 + col;
#pragma unroll
            for (int r = 0; r < 4; ++r) p[(long)r * N] = acc[i][j][r];
        }
    }
}

// ===========================================================================
// Prep kernels: build split-bf16 operands in workspace.
// ===========================================================================
// A' = [P_hi | P_hi | P_lo]  (N_ROWS x 768)
__global__ __launch_bounds__(256)
void prep_A(const float* __restrict__ P, unsigned short* __restrict__ Ap)
{
    const long i = (long)blockIdx.x * 256 + threadIdx.x;   // over N_ROWS*R_DIM
    const long n = i >> 8; const int r = (int)(i & 255);
    const float x = P[i];
    const unsigned short hi = f2bf(x);
    const unsigned short lo = f2bf(x - bf2f(hi));
    unsigned short* row = Ap + n * KP;
    row[r] = hi; row[R_DIM + r] = hi; row[2 * R_DIM + r] = lo;
}

// B' = [L_hi | L_lo | L_hi]  (K_DIM x 768)
__global__ __launch_bounds__(256)
void prep_B(const float* __restrict__ L, unsigned short* __restrict__ Bp)
{
    const long i = (long)blockIdx.x * 256 + threadIdx.x;   // over K_DIM*R_DIM
    const long k = i >> 8; const int r = (int)(i & 255);
    const float x = L[i];
    const unsigned short hi = f2bf(x);
    const unsigned short lo = f2bf(x - bf2f(hi));
    unsigned short* row = Bp + k * KP;
    row[r] = hi; row[R_DIM + r] = lo; row[2 * R_DIM + r] = hi;
}

// LT[r][k] = bf16(L[k][r])  (256 x 4096) — coalesced writes
__global__ __launch_bounds__(256)
void prep_LT(const float* __restrict__ L, unsigned short* __restrict__ LT)
{
    const long i = (long)blockIdx.x * 256 + threadIdx.x;   // over R_DIM*K_DIM
    const long r = i >> 12; const long k = i & 4095;
    LT[r * K_DIM + k] = f2bf(L[k * R_DIM + r]);
}

// ===========================================================================
// fp32 VALU GEMM (round-1) — used for K1 (P = H@W_I) and as ws fallback.
// ===========================================================================
template<bool BT>
__global__ __launch_bounds__(256)
void gemm128(const float* __restrict__ A, const float* __restrict__ B,
             float* __restrict__ C, int M, int N, int Kc)
{
    __shared__ __align__(16) float Asl[16][132];
    __shared__ __align__(16) float Bsl[16][132];

    const int tid = threadIdx.x;
    const int tx = tid & 15, ty = tid >> 4;
    const long m0 = (long)blockIdx.x * 128;
    const long n0 = (long)blockIdx.y * 128;

    float acc[8][8];
#pragma unroll
    for (int i = 0; i < 8; ++i)
#pragma unroll
        for (int j = 0; j < 8; ++j) acc[i][j] = 0.f;

    for (int k0 = 0; k0 < Kc; k0 += 16) {
#pragma unroll
        for (int q = 0; q < 2; ++q) {
            int fi = tid + 256 * q, row = fi >> 2, col = (fi & 3) * 4;
            float4 v = *(const float4*)(A + (m0 + row) * (long)Kc + k0 + col);
            Asl[col + 0][row] = v.x; Asl[col + 1][row] = v.y;
            Asl[col + 2][row] = v.z; Asl[col + 3][row] = v.w;
        }
        if (BT) {
#pragma unroll
            for (int q = 0; q < 2; ++q) {
                int fi = tid + 256 * q, row = fi >> 2, col = (fi & 3) * 4;
                float4 v = *(const float4*)(B + (n0 + row) * (long)Kc + k0 + col);
                Bsl[col + 0][row] = v.x; Bsl[col + 1][row] = v.y;
                Bsl[col + 2][row] = v.z; Bsl[col + 3][row] = v.w;
            }
        } else {
#pragma unroll
            for (int q = 0; q < 2; ++q) {
                int fi = tid + 256 * q, row = fi >> 5, col = (fi & 31) * 4;
                float4 v = *(const float4*)(B + (k0 + row) * (long)N + n0 + col);
                *(float4*)&Bsl[row][col] = v;
            }
        }
        __syncthreads();
#pragma unroll
        for (int kk = 0; kk < 16; ++kk) {
            float a[8], b[8];
            *(float4*)&a[0] = *(const float4*)&Asl[kk][ty * 8];
            *(float4*)&a[4] = *(const float4*)&Asl[kk][ty * 8 + 4];
            *(float4*)&b[0] = *(const float4*)&Bsl[kk][tx * 8];
            *(float4*)&b[4] = *(const float4*)&Bsl[kk][tx * 8 + 4];
#pragma unroll
            for (int i = 0; i < 8; ++i)
#pragma unroll
                for (int j = 0; j < 8; ++j)
                    acc[i][j] = fmaf(a[i], b[j], acc[i][j]);
        }
        __syncthreads();
    }
#pragma unroll
    for (int i = 0; i < 8; ++i) {
        float* p = C + (m0 + ty * 8 + i) * (long)N + n0 + tx * 8;
        *(float4*)p       = make_float4(acc[i][0], acc[i][1], acc[i][2], acc[i][3]);
        *(float4*)(p + 4) = make_float4(acc[i][4], acc[i][5], acc[i][6], acc[i][7]);
    }
}

// ---------------------------------------------------------------------------
// In-place row softmax over K_DIM columns, one 256-thread block per row.
// ---------------------------------------------------------------------------
__global__ __launch_bounds__(256)
void softmax_rows(float* __restrict__ Mio)
{
    const long n  = blockIdx.x;
    float* row    = Mio + n * (long)K_DIM;
    const int tid = threadIdx.x;

    float4 v[4];
    float lmax = -3.4e38f;
#pragma unroll
    for (int q = 0; q < 4; ++q) {
        v[q] = ((const float4*)row)[tid + 256 * q];
        lmax = fmaxf(lmax, fmaxf(fmaxf(v[q].x, v[q].y), fmaxf(v[q].z, v[q].w)));
    }
    __shared__ float redmax[4], redsum[4];
#pragma unroll
    for (int off = 32; off > 0; off >>= 1)
        lmax = fmaxf(lmax, __shfl_xor(lmax, off));
    if ((tid & 63) == 0) redmax[tid >> 6] = lmax;
    __syncthreads();
    const float gmax = fmaxf(fmaxf(redmax[0], redmax[1]), fmaxf(redmax[2], redmax[3]));

    float lsum = 0.f;
#pragma unroll
    for (int q = 0; q < 4; ++q) {
        v[q].x = __expf(v[q].x - gmax); v[q].y = __expf(v[q].y - gmax);
        v[q].z = __expf(v[q].z - gmax); v[q].w = __expf(v[q].w - gmax);
        lsum += v[q].x + v[q].y + v[q].z + v[q].w;
    }
#pragma unroll
    for (int off = 32; off > 0; off >>= 1)
        lsum += __shfl_xor(lsum, off);
    if ((tid & 63) == 0) redsum[tid >> 6] = lsum;
    __syncthreads();
    const float inv = 1.f / (redsum[0] + redsum[1] + redsum[2] + redsum[3]);
#pragma unroll
    for (int q = 0; q < 4; ++q) {
        v[q].x *= inv; v[q].y *= inv; v[q].z *= inv; v[q].w *= inv;
        ((float4*)row)[tid + 256 * q] = v[q];
    }
}

// ===========================================================================
extern "C" void kernel_launch(void* const* d_in, const int* in_sizes, int n_in,
                              void* d_out, int out_size, void* d_ws, size_t ws_size,
                              hipStream_t stream)
{
    const float* H  = (const float*)d_in[0];
    const float* L  = (const float*)d_in[1];
    const float* Wi = (const float*)d_in[2];

    float* Cout = (float*)d_out;                           // N x R
    float* Aout = (float*)d_out + (size_t)N_ROWS * R_DIM;  // N x K

    const size_t szAp = (size_t)N_ROWS * KP * 2;   // 48 MiB
    const size_t szBp = (size_t)K_DIM * KP * 2;    //  6 MiB
    const size_t szLT = (size_t)R_DIM * K_DIM * 2; //  2 MiB

    if (ws_size >= szAp + szBp + szLT) {
        unsigned short* Ap = (unsigned short*)d_ws;
        unsigned short* Bp = (unsigned short*)((char*)d_ws + szAp);
        unsigned short* LT = (unsigned short*)((char*)d_ws + szAp + szBp);

        // K1: P = H@W_I (fp32 VALU), stored in C slot
        gemm128<false><<<dim3(N_ROWS / 128, R_DIM / 128), 256, 0, stream>>>(
            H, Wi, Cout, N_ROWS, R_DIM, R_DIM);
        // Prep split operands
        prep_A<<<dim3((N_ROWS * R_DIM) / 256), 256, 0, stream>>>(Cout, Ap);
        prep_B<<<dim3((K_DIM * R_DIM) / 256), 256, 0, stream>>>(L, Bp);
        prep_LT<<<dim3((R_DIM * K_DIM) / 256), 256, 0, stream>>>(L, LT);
        // K2: logits M = A'·B'^T (3-term split bf16 MFMA), K'=768
        gemm_mfma_nt<<<dim3(N_ROWS / 128, K_DIM / 128), 256, 0, stream>>>(
            Ap, Bp, Aout, N_ROWS, K_DIM, KP);
        // K3: softmax in place
        softmax_rows<<<dim3(N_ROWS), 256, 0, stream>>>(Aout);
        // K4: C = A_sm @ L (bf16 MFMA, A converted during staging)
        gemm_mfma_a32<<<dim3(N_ROWS / 128, R_DIM / 128), 256, 0, stream>>>(
            Aout, LT, Cout, N_ROWS, R_DIM, K_DIM);
    } else {
        // Fallback: round-1 fp32 path
        gemm128<false><<<dim3(N_ROWS / 128, R_DIM / 128), 256, 0, stream>>>(
            H, Wi, Cout, N_ROWS, R_DIM, R_DIM);
        gemm128<true><<<dim3(N_ROWS / 128, K_DIM / 128), 256, 0, stream>>>(
            Cout, L, Aout, N_ROWS, K_DIM, R_DIM);
        softmax_rows<<<dim3(N_ROWS), 256, 0, stream>>>(Aout);
        gemm128<false><<<dim3(N_ROWS / 128, R_DIM / 128), 256, 0, stream>>>(
            Aout, L, Cout, N_ROWS, R_DIM, K_DIM);
    }
}